// Round 5
// baseline (426.990 us; speedup 1.0000x reference)
//
#include <hip/hip_runtime.h>
#include <hip/hip_bf16.h>
#include <stdint.h>

#define BATCH 4
#define SEQ 2048
#define DMODEL 512
#define NHEAD 8
#define HD 64

using f32x4 = __attribute__((ext_vector_type(4))) float;
using bfrag = __attribute__((ext_vector_type(8))) short;

__device__ __forceinline__ short f2bf(float f) {
  uint32_t x = __builtin_bit_cast(uint32_t, f);
  uint32_t r = (x + 0x7fffu + ((x >> 16) & 1u)) >> 16;
  return (short)r;
}
__device__ __forceinline__ float bf2f(short s) {
  return __builtin_bit_cast(float, ((uint32_t)(uint16_t)s) << 16);
}

// ---------------- dtype sniffer (proven: flags 1 => inputs are float32) ------
__global__ void sniff(const uint32_t* __restrict__ x, int* __restrict__ flag) {
  const int tid = threadIdx.x;
  bool bad = false;
#pragma unroll
  for (int i = 0; i < 8; ++i) {
    const uint32_t w = x[tid * 8 + i];
    const uint32_t elo = (w >> 7) & 0xffu;
    const uint32_t ehi = (w >> 23) & 0xffu;
    bad |= (elo >= 0xB0u) | (ehi >= 0xB0u);
  }
  const unsigned long long m = __ballot(bad);
  if (tid == 0) *flag = (m != 0ull) ? 1 : 0;
}

// ---------------- embeddings -> bf16 (f32 downconvert or bf16 copy) ----------
__global__ __launch_bounds__(256) void conv_x(const void* __restrict__ in,
                                              short* __restrict__ out,
                                              const int* __restrict__ flag) {
  const int i = (blockIdx.x * 256 + threadIdx.x) * 8;
  if (*flag) {
    const float* f = (const float*)in;
    short r[8];
#pragma unroll
    for (int j = 0; j < 8; ++j) r[j] = f2bf(f[i + j]);
    *(bfrag*)&out[i] = *(bfrag*)r;
  } else {
    *(bfrag*)&out[i] = *(const bfrag*)&((const short*)in)[i];
  }
}

// ---------------- weight transpose (+convert): Wt[n][k] = W[k][n] ------------
__global__ __launch_bounds__(256) void transpose_w(const void* __restrict__ in,
                                                   short* __restrict__ out,
                                                   const int* __restrict__ flag) {
  __shared__ short t[32][33];
  const int n0 = blockIdx.x * 32, k0 = blockIdx.y * 32;
  const int tx = threadIdx.x, ty = threadIdx.y;
  const bool isf32 = (*flag != 0);
#pragma unroll
  for (int i = ty; i < 32; i += 8) {
    const int idx = (k0 + i) * DMODEL + n0 + tx;
    t[i][tx] = isf32 ? f2bf(((const float*)in)[idx]) : ((const short*)in)[idx];
  }
  __syncthreads();
#pragma unroll
  for (int i = ty; i < 32; i += 8) out[(n0 + i) * DMODEL + k0 + tx] = t[tx][i];
}

// ---------------- QKV projection GEMM (bf16 MFMA) ----------------------------
__global__ __launch_bounds__(256) void gemm_qkv(const short* __restrict__ X,
                                                const short* __restrict__ WtAll,
                                                short* __restrict__ Qo,
                                                short* __restrict__ Ko,
                                                short* __restrict__ Vo) {
  __shared__ __align__(16) short As[64 * 40];
  __shared__ __align__(16) short Bs[64 * 40];
  const int which = blockIdx.z;
  const short* Wt = WtAll + which * DMODEL * DMODEL;
  const int m0 = blockIdx.y * 64, n0 = blockIdx.x * 64;
  const int tid = threadIdx.x, lane = tid & 63, wave = tid >> 6;
  const int srow = tid >> 2, sseg = tid & 3;
  f32x4 acc[4] = {};
  for (int kc = 0; kc < DMODEL; kc += 32) {
    *(bfrag*)&As[srow * 40 + sseg * 8] =
        *(const bfrag*)&X[(m0 + srow) * DMODEL + kc + sseg * 8];
    *(bfrag*)&Bs[srow * 40 + sseg * 8] =
        *(const bfrag*)&Wt[(n0 + srow) * DMODEL + kc + sseg * 8];
    __syncthreads();
    bfrag a = *(const bfrag*)&As[(wave * 16 + (lane & 15)) * 40 + (lane >> 4) * 8];
#pragma unroll
    for (int t = 0; t < 4; ++t) {
      bfrag b = *(const bfrag*)&Bs[(t * 16 + (lane & 15)) * 40 + (lane >> 4) * 8];
      acc[t] = __builtin_amdgcn_mfma_f32_16x16x32_bf16(a, b, acc[t], 0, 0, 0);
    }
    __syncthreads();
  }
  short* O = (which == 0) ? Qo : (which == 1) ? Ko : Vo;
#pragma unroll
  for (int t = 0; t < 4; ++t) {
    const int col = n0 + t * 16 + (lane & 15);
    const int h = col >> 6, d = col & 63;
#pragma unroll
    for (int r = 0; r < 4; ++r) {
      const int row = m0 + wave * 16 + (lane >> 4) * 4 + r;  // = b*SEQ + s
      const int b = row >> 11, s = row & 2047;
      O[((b * NHEAD + h) * SEQ + s) * HD + d] = f2bf(acc[t][r]);
    }
  }
}

// ---------------- output projection GEMM: bf16 in, FLOAT32 out ---------------
__global__ __launch_bounds__(256) void gemm_out(const short* __restrict__ X,
                                                const short* __restrict__ Wt,
                                                float* __restrict__ O) {
  __shared__ __align__(16) short As[64 * 40];
  __shared__ __align__(16) short Bs[64 * 40];
  const int m0 = blockIdx.y * 64, n0 = blockIdx.x * 64;
  const int tid = threadIdx.x, lane = tid & 63, wave = tid >> 6;
  const int srow = tid >> 2, sseg = tid & 3;
  f32x4 acc[4] = {};
  for (int kc = 0; kc < DMODEL; kc += 32) {
    *(bfrag*)&As[srow * 40 + sseg * 8] =
        *(const bfrag*)&X[(m0 + srow) * DMODEL + kc + sseg * 8];
    *(bfrag*)&Bs[srow * 40 + sseg * 8] =
        *(const bfrag*)&Wt[(n0 + srow) * DMODEL + kc + sseg * 8];
    __syncthreads();
    bfrag a = *(const bfrag*)&As[(wave * 16 + (lane & 15)) * 40 + (lane >> 4) * 8];
#pragma unroll
    for (int t = 0; t < 4; ++t) {
      bfrag b = *(const bfrag*)&Bs[(t * 16 + (lane & 15)) * 40 + (lane >> 4) * 8];
      acc[t] = __builtin_amdgcn_mfma_f32_16x16x32_bf16(a, b, acc[t], 0, 0, 0);
    }
    __syncthreads();
  }
#pragma unroll
  for (int t = 0; t < 4; ++t) {
    const int col = n0 + t * 16 + (lane & 15);
#pragma unroll
    for (int r = 0; r < 4; ++r) {
      const int row = m0 + wave * 16 + (lane >> 4) * 4 + r;
      O[(size_t)row * DMODEL + col] = acc[t][r];  // float32 store
    }
  }
}

// ---------------- mean of V over all keys (for tq==0 degenerate rows) --------
// ref: fully-masked q-row => softmax uniform over ALL 2048 keys => mean(V).
__global__ __launch_bounds__(256) void meanv(const short* __restrict__ V,
                                             float* __restrict__ mv) {
  __shared__ float red[256];
  const int bh = blockIdx.x, tid = threadIdx.x;
  const int d = tid & 63, seg = tid >> 6;
  const size_t base = (size_t)bh * SEQ * HD;
  float s = 0.f;
  for (int k = seg * 512; k < seg * 512 + 512; ++k) s += bf2f(V[base + (size_t)k * HD + d]);
  red[tid] = s;
  __syncthreads();
  if (tid < 64)
    mv[bh * 64 + d] = (red[tid] + red[tid + 64] + red[tid + 128] + red[tid + 192]) * (1.f / 2048.f);
}

// ---------------- flash attention: causal skip + XOR-swizzled Vt/P ----------
// Vts layout:  addr(d,k) = d*64 + (((k>>3) ^ (d>>3)) & 7)*8 + (k&7)
//   write (fixed j): bank = ((wave^sg)*4 + q/2) -> 32 banks, 2-lane dword-merge = conflict-free
//   read (b128):     8 granule-groups x 4 dwords = 8/bank = b128 structural floor
// Ps layout (per wave): m*64 + (((k>>3) ^ (m&7)) & 7)*8 + (k&7)
__global__ __launch_bounds__(256) void attn(const short* __restrict__ Q,
                                            const short* __restrict__ K,
                                            const short* __restrict__ V,
                                            const int* __restrict__ tmask,
                                            const float* __restrict__ meanV,
                                            short* __restrict__ ctx) {
  __shared__ __align__(16) short Qs[64 * 72];
  __shared__ __align__(16) short Ks[64 * 72];
  __shared__ __align__(16) short Vts[64 * 64];
  __shared__ __align__(16) short Ps[4 * 16 * 64];
  __shared__ int tmq[64];
  __shared__ int tmk[64];
  const int bh = blockIdx.y, b = bh >> 3, h = bh & 7;
  // load-balance remap: pair short blocks with long ones ({0,31},{1,30},...)
  const int xr = blockIdx.x;
  const int qi = (xr & 1) ? (31 - (xr >> 1)) : (xr >> 1);
  const int q0 = qi * 64;
  const int tid = threadIdx.x, lane = tid & 63, wave = tid >> 6;
  const int l15 = lane & 15, quad = lane >> 4;
  const size_t base = (size_t)bh * SEQ * HD;

  for (int i = tid; i < 512; i += 256) {
    const int r = i >> 3, sg = i & 7;
    *(bfrag*)&Qs[r * 72 + sg * 8] = *(const bfrag*)&Q[base + (size_t)(q0 + r) * HD + sg * 8];
  }
  if (tid < 64) tmq[tid] = tmask[b * SEQ + q0 + tid];

  f32x4 accO[4] = {};
  float mrow[4], lrow[4];
#pragma unroll
  for (int r = 0; r < 4; ++r) { mrow[r] = -1e30f; lrow[r] = 0.f; }
  const int qrow_loc = wave * 16 + quad * 4;  // + r

  for (int kc = 0; kc <= q0; kc += 64) {
    __syncthreads();  // prev PV reads of Ks/Vts done before overwrite
    for (int i = tid; i < 512; i += 256) {
      const int kr = i >> 3, sg = i & 7;
      *(bfrag*)&Ks[kr * 72 + sg * 8] =
          *(const bfrag*)&K[base + (size_t)(kc + kr) * HD + sg * 8];
      bfrag v = *(const bfrag*)&V[base + (size_t)(kc + kr) * HD + sg * 8];
      short* vd = &Vts[(((kr >> 3) ^ sg) & 7) * 8 + (kr & 7)];
#pragma unroll
      for (int j = 0; j < 8; ++j) vd[(sg * 8 + j) * 64] = v[j];
    }
    if (tid < 64) tmk[tid] = tmask[b * SEQ + kc + tid];
    __syncthreads();

    // S = Q @ K^T (this wave: 16 q-rows x 64 k-cols)
    f32x4 sacc[4] = {};
#pragma unroll
    for (int ds = 0; ds < 2; ++ds) {
      bfrag a = *(const bfrag*)&Qs[(wave * 16 + l15) * 72 + ds * 32 + quad * 8];
#pragma unroll
      for (int t = 0; t < 4; ++t) {
        bfrag bb = *(const bfrag*)&Ks[(t * 16 + l15) * 72 + ds * 32 + quad * 8];
        sacc[t] = __builtin_amdgcn_mfma_f32_16x16x32_bf16(a, bb, sacc[t], 0, 0, 0);
      }
    }

    // masked online softmax per row (tq handled in epilogue via meanV override)
#pragma unroll
    for (int r = 0; r < 4; ++r) {
      const int qg = q0 + qrow_loc + r;
      const int m = quad * 4 + r;  // local row in this wave's 16
      float sv[4];
      float mx = -1e30f;
#pragma unroll
      for (int t = 0; t < 4; ++t) {
        const int kl = t * 16 + l15;
        const bool ok = (kc + kl <= qg) && (tmk[kl] != 0);
        sv[t] = ok ? sacc[t][r] * 0.125f : -1e30f;
        mx = fmaxf(mx, sv[t]);
      }
#pragma unroll
      for (int o = 1; o < 16; o <<= 1) mx = fmaxf(mx, __shfl_xor(mx, o));
      const float mnew = fmaxf(mrow[r], mx);
      float rsum = 0.f;
#pragma unroll
      for (int t = 0; t < 4; ++t) {
        const float p = __expf(sv[t] - mnew);
        rsum += p;
        const int g = (t * 2 + (l15 >> 3)) ^ (m & 7);  // k>>3 XOR m&7
        Ps[wave * 1024 + m * 64 + (g & 7) * 8 + (l15 & 7)] = f2bf(p);
      }
#pragma unroll
      for (int o = 1; o < 16; o <<= 1) rsum += __shfl_xor(rsum, o);
      const float alpha = __expf(mrow[r] - mnew);
      mrow[r] = mnew;
      lrow[r] = lrow[r] * alpha + rsum;
#pragma unroll
      for (int t = 0; t < 4; ++t) accO[t][r] *= alpha;
    }
    __syncthreads();  // P LDS write -> read

    // O += P @ V
#pragma unroll
    for (int ks = 0; ks < 2; ++ks) {
      const int gp = ((ks * 4 + quad) ^ (l15 & 7)) & 7;
      bfrag pa = *(const bfrag*)&Ps[wave * 1024 + l15 * 64 + gp * 8];
#pragma unroll
      for (int t = 0; t < 4; ++t) {
        const int d = t * 16 + l15;
        const int gv = ((ks * 4 + quad) ^ (d >> 3)) & 7;
        bfrag vb = *(const bfrag*)&Vts[d * 64 + gv * 8];
        accO[t] = __builtin_amdgcn_mfma_f32_16x16x32_bf16(pa, vb, accO[t], 0, 0, 0);
      }
    }
  }

  // epilogue: tq==1 -> accO/l ; tq==0 -> mean of all V (exact reference semantics)
#pragma unroll
  for (int t = 0; t < 4; ++t) {
    const int d = t * 16 + l15;
    const float mvd = meanV[bh * 64 + d];
#pragma unroll
    for (int r = 0; r < 4; ++r) {
      const int row = qrow_loc + r;
      const int qg = q0 + row;
      float val = accO[t][r] / lrow[r];
      if (tmq[row] == 0) val = mvd;
      ctx[((size_t)(b * SEQ + qg)) * DMODEL + h * HD + d] = f2bf(val);
    }
  }
}

extern "C" void kernel_launch(void* const* d_in, const int* in_sizes, int n_in,
                              void* d_out, int out_size, void* d_ws, size_t ws_size,
                              hipStream_t stream) {
  const void* X = d_in[0];
  const int* tmask = (const int*)d_in[1];
  const void* Wq = d_in[2];
  const void* Wk = d_in[3];
  const void* Wv = d_in[4];
  const void* Wo = d_in[5];
  float* out = (float*)d_out;  // reference returns float32
  char* ws = (char*)d_ws;

  const size_t WELEM = (size_t)DMODEL * DMODEL;           // 262144
  const size_t TELEM = (size_t)BATCH * NHEAD * SEQ * HD;  // 4,194,304

  int* flag = (int*)ws;                        // [0, 4 KB)
  float* mv = (float*)(ws + 4096);             // 8 KB: meanV[32][64]
  short* wt = (short*)(ws + 4096 + 8192);      // 2 MB: 4 transposed bf16 weights
  short* Xb = (short*)(ws + 4096 + 8192 + 2097152);
  short* Qb = Xb + TELEM;
  short* Kb = Qb + TELEM;
  short* Vb = Kb + TELEM;
  short* Cb = Vb + TELEM;

  sniff<<<1, 64, 0, stream>>>((const uint32_t*)X, flag);
  conv_x<<<(int)(TELEM / (256 * 8)), 256, 0, stream>>>(X, Xb, flag);
  dim3 tb(32, 8);
  transpose_w<<<dim3(16, 16), tb, 0, stream>>>(Wq, wt, flag);
  transpose_w<<<dim3(16, 16), tb, 0, stream>>>(Wk, wt + WELEM, flag);
  transpose_w<<<dim3(16, 16), tb, 0, stream>>>(Wv, wt + 2 * WELEM, flag);
  transpose_w<<<dim3(16, 16), tb, 0, stream>>>(Wo, wt + 3 * WELEM, flag);
  gemm_qkv<<<dim3(8, 128, 3), 256, 0, stream>>>(Xb, wt, Qb, Kb, Vb);
  meanv<<<BATCH * NHEAD, 256, 0, stream>>>(Vb, mv);
  attn<<<dim3(SEQ / 64, BATCH * NHEAD), 256, 0, stream>>>(Qb, Kb, Vb, tmask, mv, Cb);
  gemm_out<<<dim3(8, 128), 256, 0, stream>>>(Cb, wt + 3 * WELEM, out);
}

// Round 6
// 266.466 us; speedup vs baseline: 1.6024x; 1.6024x over previous
//
#include <hip/hip_runtime.h>
#include <hip/hip_bf16.h>
#include <stdint.h>

#define BATCH 4
#define SEQ 2048
#define DMODEL 512
#define NHEAD 8
#define HD 64

// fixed-max softmax constants: p = exp(s/8 - 16) computed as exp2(s*C1 + BIAS2)
#define C1 0.18033688f     // 0.125 * log2(e)
#define BIAS2 -23.0831207f // -16 * log2(e)

using f32x4 = __attribute__((ext_vector_type(4))) float;
using bfrag = __attribute__((ext_vector_type(8))) short;

__device__ __forceinline__ short f2bf(float f) {
  uint32_t x = __builtin_bit_cast(uint32_t, f);
  uint32_t r = (x + 0x7fffu + ((x >> 16) & 1u)) >> 16;
  return (short)r;
}
__device__ __forceinline__ short f2bf_fast(float f) {  // round-half-up, 2 ops
  return (short)((__builtin_bit_cast(uint32_t, f) + 0x8000u) >> 16);
}
__device__ __forceinline__ float bf2f(short s) {
  return __builtin_bit_cast(float, ((uint32_t)(uint16_t)s) << 16);
}

// ---------------- dtype sniffer (proven: flags 1 => inputs are float32) ------
__global__ void sniff(const uint32_t* __restrict__ x, int* __restrict__ flag) {
  const int tid = threadIdx.x;
  bool bad = false;
#pragma unroll
  for (int i = 0; i < 8; ++i) {
    const uint32_t w = x[tid * 8 + i];
    const uint32_t elo = (w >> 7) & 0xffu;
    const uint32_t ehi = (w >> 23) & 0xffu;
    bad |= (elo >= 0xB0u) | (ehi >= 0xB0u);
  }
  const unsigned long long m = __ballot(bad);
  if (tid == 0) *flag = (m != 0ull) ? 1 : 0;
}

// ---------------- embeddings -> bf16 (f32 downconvert or bf16 copy) ----------
__global__ __launch_bounds__(256) void conv_x(const void* __restrict__ in,
                                              short* __restrict__ out,
                                              const int* __restrict__ flag) {
  const int i = (blockIdx.x * 256 + threadIdx.x) * 8;
  if (*flag) {
    const float* f = (const float*)in;
    short r[8];
#pragma unroll
    for (int j = 0; j < 8; ++j) r[j] = f2bf(f[i + j]);
    *(bfrag*)&out[i] = *(bfrag*)r;
  } else {
    *(bfrag*)&out[i] = *(const bfrag*)&((const short*)in)[i];
  }
}

// ---------------- weight transpose (+convert): Wt[n][k] = W[k][n] ------------
__global__ __launch_bounds__(256) void transpose_w(const void* __restrict__ in,
                                                   short* __restrict__ out,
                                                   const int* __restrict__ flag) {
  __shared__ short t[32][33];
  const int n0 = blockIdx.x * 32, k0 = blockIdx.y * 32;
  const int tx = threadIdx.x, ty = threadIdx.y;
  const bool isf32 = (*flag != 0);
#pragma unroll
  for (int i = ty; i < 32; i += 8) {
    const int idx = (k0 + i) * DMODEL + n0 + tx;
    t[i][tx] = isf32 ? f2bf(((const float*)in)[idx]) : ((const short*)in)[idx];
  }
  __syncthreads();
#pragma unroll
  for (int i = ty; i < 32; i += 8) out[(n0 + i) * DMODEL + k0 + tx] = t[tx][i];
}

// ---------------- QKV projection GEMM (bf16 MFMA) ----------------------------
__global__ __launch_bounds__(256) void gemm_qkv(const short* __restrict__ X,
                                                const short* __restrict__ WtAll,
                                                short* __restrict__ Qo,
                                                short* __restrict__ Ko,
                                                short* __restrict__ Vo) {
  __shared__ __align__(16) short As[64 * 40];
  __shared__ __align__(16) short Bs[64 * 40];
  const int which = blockIdx.z;
  const short* Wt = WtAll + which * DMODEL * DMODEL;
  const int m0 = blockIdx.y * 64, n0 = blockIdx.x * 64;
  const int tid = threadIdx.x, lane = tid & 63, wave = tid >> 6;
  const int srow = tid >> 2, sseg = tid & 3;
  f32x4 acc[4] = {};
  for (int kc = 0; kc < DMODEL; kc += 32) {
    *(bfrag*)&As[srow * 40 + sseg * 8] =
        *(const bfrag*)&X[(m0 + srow) * DMODEL + kc + sseg * 8];
    *(bfrag*)&Bs[srow * 40 + sseg * 8] =
        *(const bfrag*)&Wt[(n0 + srow) * DMODEL + kc + sseg * 8];
    __syncthreads();
    bfrag a = *(const bfrag*)&As[(wave * 16 + (lane & 15)) * 40 + (lane >> 4) * 8];
#pragma unroll
    for (int t = 0; t < 4; ++t) {
      bfrag b = *(const bfrag*)&Bs[(t * 16 + (lane & 15)) * 40 + (lane >> 4) * 8];
      acc[t] = __builtin_amdgcn_mfma_f32_16x16x32_bf16(a, b, acc[t], 0, 0, 0);
    }
    __syncthreads();
  }
  short* O = (which == 0) ? Qo : (which == 1) ? Ko : Vo;
#pragma unroll
  for (int t = 0; t < 4; ++t) {
    const int col = n0 + t * 16 + (lane & 15);
    const int h = col >> 6, d = col & 63;
#pragma unroll
    for (int r = 0; r < 4; ++r) {
      const int row = m0 + wave * 16 + (lane >> 4) * 4 + r;  // = b*SEQ + s
      const int b = row >> 11, s = row & 2047;
      O[((b * NHEAD + h) * SEQ + s) * HD + d] = f2bf(acc[t][r]);
    }
  }
}

// ---------------- output projection GEMM: bf16 in, FLOAT32 out ---------------
__global__ __launch_bounds__(256) void gemm_out(const short* __restrict__ X,
                                                const short* __restrict__ Wt,
                                                float* __restrict__ O) {
  __shared__ __align__(16) short As[64 * 40];
  __shared__ __align__(16) short Bs[64 * 40];
  const int m0 = blockIdx.y * 64, n0 = blockIdx.x * 64;
  const int tid = threadIdx.x, lane = tid & 63, wave = tid >> 6;
  const int srow = tid >> 2, sseg = tid & 3;
  f32x4 acc[4] = {};
  for (int kc = 0; kc < DMODEL; kc += 32) {
    *(bfrag*)&As[srow * 40 + sseg * 8] =
        *(const bfrag*)&X[(m0 + srow) * DMODEL + kc + sseg * 8];
    *(bfrag*)&Bs[srow * 40 + sseg * 8] =
        *(const bfrag*)&Wt[(n0 + srow) * DMODEL + kc + sseg * 8];
    __syncthreads();
    bfrag a = *(const bfrag*)&As[(wave * 16 + (lane & 15)) * 40 + (lane >> 4) * 8];
#pragma unroll
    for (int t = 0; t < 4; ++t) {
      bfrag b = *(const bfrag*)&Bs[(t * 16 + (lane & 15)) * 40 + (lane >> 4) * 8];
      acc[t] = __builtin_amdgcn_mfma_f32_16x16x32_bf16(a, b, acc[t], 0, 0, 0);
    }
    __syncthreads();
  }
#pragma unroll
  for (int t = 0; t < 4; ++t) {
    const int col = n0 + t * 16 + (lane & 15);
#pragma unroll
    for (int r = 0; r < 4; ++r) {
      const int row = m0 + wave * 16 + (lane >> 4) * 4 + r;
      O[(size_t)row * DMODEL + col] = acc[t][r];  // float32 store
    }
  }
}

// ---------------- mean of V over all keys — vectorized, ILP-friendly ---------
// r5's serial-accumulate version was ~133 us (dependent-chain latency-bound).
// Now: 8 independent vector accumulators/thread, bfrag loads, LDS reduce.
__global__ __launch_bounds__(256) void meanv(const short* __restrict__ V,
                                             float* __restrict__ mv) {
  __shared__ float red[32][64];
  const int bh = blockIdx.x, tid = threadIdx.x;
  const int sg = tid & 7, kk = tid >> 3;  // 8 d-segments x 32 k-slots
  const size_t base = (size_t)bh * SEQ * HD;
  float acc[8] = {};
  for (int k = kk; k < SEQ; k += 32) {
    bfrag v = *(const bfrag*)&V[base + (size_t)k * HD + sg * 8];
#pragma unroll
    for (int j = 0; j < 8; ++j) acc[j] += bf2f(v[j]);
  }
#pragma unroll
  for (int j = 0; j < 8; ++j) red[kk][sg * 8 + j] = acc[j];
  __syncthreads();
  if (tid < 64) {
    float s = 0.f;
#pragma unroll
    for (int k2 = 0; k2 < 32; ++k2) s += red[k2][tid];
    mv[bh * 64 + tid] = s * (1.f / 2048.f);
  }
}

// ---------------- flash attention v3 ----------------------------------------
// Fixed-max softmax (no running max, no in-loop shfls, deferred l-reduction),
// peeled diagonal chunk, register prefetch of next K/V, 2 barriers/chunk.
__global__ __launch_bounds__(256) void attn(const short* __restrict__ Q,
                                            const short* __restrict__ K,
                                            const short* __restrict__ V,
                                            const int* __restrict__ tmask,
                                            const float* __restrict__ meanV,
                                            short* __restrict__ ctx) {
  __shared__ __align__(16) short Qs[64 * 72];
  __shared__ __align__(16) short Ks[64 * 72];
  __shared__ __align__(16) short Vts[64 * 64];
  __shared__ __align__(16) short Ps[4 * 16 * 64];
  __shared__ int tmq[64];
  __shared__ int tmk[64];
  const int bh = blockIdx.y, b = bh >> 3, h = bh & 7;
  const int xr = blockIdx.x;
  const int qi = (xr & 1) ? (31 - (xr >> 1)) : (xr >> 1);  // pair long+short
  const int q0 = qi * 64;
  const int tid = threadIdx.x, lane = tid & 63, wave = tid >> 6;
  const int l15 = lane & 15, quad = lane >> 4;
  const size_t base = (size_t)bh * SEQ * HD;

  for (int i = tid; i < 512; i += 256) {
    const int r = i >> 3, sg = i & 7;
    *(bfrag*)&Qs[r * 72 + sg * 8] = *(const bfrag*)&Q[base + (size_t)(q0 + r) * HD + sg * 8];
  }
  if (tid < 64) tmq[tid] = tmask[b * SEQ + q0 + tid];

  f32x4 accO[4] = {};
  float lrow[4] = {0.f, 0.f, 0.f, 0.f};

  const int kr0 = tid >> 3, sgp = tid & 7;  // each thread stages rows kr0, kr0+32
  bfrag kA, kB, vA, vB;
  int tmreg = 0;

  auto prefetch = [&](int kc) {
    const size_t o0 = base + (size_t)(kc + kr0) * HD + sgp * 8;
    kA = *(const bfrag*)&K[o0];
    vA = *(const bfrag*)&V[o0];
    kB = *(const bfrag*)&K[o0 + 32 * HD];
    vB = *(const bfrag*)&V[o0 + 32 * HD];
    if (tid < 64) tmreg = tmask[b * SEQ + kc + tid];
  };
  auto store_lds = [&]() {
    *(bfrag*)&Ks[kr0 * 72 + sgp * 8] = kA;
    *(bfrag*)&Ks[(kr0 + 32) * 72 + sgp * 8] = kB;
    short* vd0 = &Vts[(((kr0 >> 3) ^ sgp) & 7) * 8 + (kr0 & 7)];
    short* vd1 = &Vts[((((kr0 >> 3) + 4) ^ sgp) & 7) * 8 + (kr0 & 7)];
#pragma unroll
    for (int j = 0; j < 8; ++j) {
      vd0[(sgp * 8 + j) * 64] = vA[j];
      vd1[(sgp * 8 + j) * 64] = vB[j];
    }
    if (tid < 64) tmk[tid] = tmreg;
  };
  auto compute = [&](bool diag) {
    f32x4 sacc[4] = {};
#pragma unroll
    for (int ds = 0; ds < 2; ++ds) {
      bfrag a = *(const bfrag*)&Qs[(wave * 16 + l15) * 72 + ds * 32 + quad * 8];
#pragma unroll
      for (int t = 0; t < 4; ++t) {
        bfrag bb = *(const bfrag*)&Ks[(t * 16 + l15) * 72 + ds * 32 + quad * 8];
        sacc[t] = __builtin_amdgcn_mfma_f32_16x16x32_bf16(a, bb, sacc[t], 0, 0, 0);
      }
    }
    float badd[4];
#pragma unroll
    for (int t = 0; t < 4; ++t) badd[t] = tmk[t * 16 + l15] ? BIAS2 : -1e30f;
#pragma unroll
    for (int r = 0; r < 4; ++r) {
      const int m = quad * 4 + r;
#pragma unroll
      for (int t = 0; t < 4; ++t) {
        float p = exp2f(fmaf(sacc[t][r], C1, badd[t]));
        if (diag && (t * 16 + l15 > wave * 16 + m)) p = 0.f;  // causal, diag chunk only
        lrow[r] += p;
        const int g = ((t * 2 + (l15 >> 3)) ^ m) & 7;
        Ps[wave * 1024 + m * 64 + g * 8 + (l15 & 7)] = f2bf_fast(p);
      }
    }
    // Ps is wave-private; same-wave DS ops are ordered -> no barrier needed.
#pragma unroll
    for (int ks = 0; ks < 2; ++ks) {
      const int gp = ((ks * 4 + quad) ^ (l15 & 7)) & 7;
      bfrag pa = *(const bfrag*)&Ps[wave * 1024 + l15 * 64 + gp * 8];
#pragma unroll
      for (int t = 0; t < 4; ++t) {
        const int d = t * 16 + l15;
        const int gv = ((ks * 4 + quad) ^ (d >> 3)) & 7;
        bfrag vb = *(const bfrag*)&Vts[d * 64 + gv * 8];
        accO[t] = __builtin_amdgcn_mfma_f32_16x16x32_bf16(pa, vb, accO[t], 0, 0, 0);
      }
    }
  };

  prefetch(0);
  for (int kc = 0; kc < q0; kc += 64) {  // interior chunks: no causal check
    __syncthreads();                     // prev PV reads of Ks/Vts done
    store_lds();
    prefetch(kc + 64);
    __syncthreads();                     // LDS ready
    compute(false);
  }
  __syncthreads();                       // diagonal chunk (kc == q0)
  store_lds();
  __syncthreads();
  compute(true);

  // deferred l-reduction (over the 16 l15-lanes of each quad-row)
#pragma unroll
  for (int r = 0; r < 4; ++r) {
    float l = lrow[r];
    l += __shfl_xor(l, 1);
    l += __shfl_xor(l, 2);
    l += __shfl_xor(l, 4);
    l += __shfl_xor(l, 8);
    lrow[r] = 1.f / l;
  }
  const int qrow_loc = wave * 16 + quad * 4;
#pragma unroll
  for (int t = 0; t < 4; ++t) {
    const int d = t * 16 + l15;
    const float mvd = meanV[bh * 64 + d];
#pragma unroll
    for (int r = 0; r < 4; ++r) {
      const int row = qrow_loc + r;
      float val = accO[t][r] * lrow[r];
      if (tmq[row] == 0) val = mvd;  // fully-masked q-row: uniform over ALL keys
      ctx[((size_t)(b * SEQ + q0 + row)) * DMODEL + h * HD + d] = f2bf(val);
    }
  }
}

extern "C" void kernel_launch(void* const* d_in, const int* in_sizes, int n_in,
                              void* d_out, int out_size, void* d_ws, size_t ws_size,
                              hipStream_t stream) {
  const void* X = d_in[0];
  const int* tmask = (const int*)d_in[1];
  const void* Wq = d_in[2];
  const void* Wk = d_in[3];
  const void* Wv = d_in[4];
  const void* Wo = d_in[5];
  float* out = (float*)d_out;  // reference returns float32
  char* ws = (char*)d_ws;

  const size_t WELEM = (size_t)DMODEL * DMODEL;           // 262144
  const size_t TELEM = (size_t)BATCH * NHEAD * SEQ * HD;  // 4,194,304

  int* flag = (int*)ws;                        // [0, 4 KB)
  float* mv = (float*)(ws + 4096);             // 8 KB: meanV[32][64]
  short* wt = (short*)(ws + 4096 + 8192);      // 2 MB: 4 transposed bf16 weights
  short* Xb = (short*)(ws + 4096 + 8192 + 2097152);
  short* Qb = Xb + TELEM;
  short* Kb = Qb + TELEM;
  short* Vb = Kb + TELEM;
  short* Cb = Vb + TELEM;

  sniff<<<1, 64, 0, stream>>>((const uint32_t*)X, flag);
  conv_x<<<(int)(TELEM / (256 * 8)), 256, 0, stream>>>(X, Xb, flag);
  dim3 tb(32, 8);
  transpose_w<<<dim3(16, 16), tb, 0, stream>>>(Wq, wt, flag);
  transpose_w<<<dim3(16, 16), tb, 0, stream>>>(Wk, wt + WELEM, flag);
  transpose_w<<<dim3(16, 16), tb, 0, stream>>>(Wv, wt + 2 * WELEM, flag);
  transpose_w<<<dim3(16, 16), tb, 0, stream>>>(Wo, wt + 3 * WELEM, flag);
  gemm_qkv<<<dim3(8, 128, 3), 256, 0, stream>>>(Xb, wt, Qb, Kb, Vb);
  meanv<<<BATCH * NHEAD, 256, 0, stream>>>(Vb, mv);
  attn<<<dim3(SEQ / 64, BATCH * NHEAD), 256, 0, stream>>>(Qb, Kb, Vb, tmask, mv, Cb);
  gemm_out<<<dim3(8, 128), 256, 0, stream>>>(Cb, wt + 3 * WELEM, out);
}